// Round 1
// baseline (359.889 us; speedup 1.0000x reference)
//
#include <hip/hip_runtime.h>

// ---------------------------------------------------------------------------
// CrossAttention: O = softmax((x1 Wq)(x2 Wk)^T / 32) (x2 Wv)
// S1=S2=4096, D_IN=D_KQ=D_V=1024, fp32 in/out.
// Precision scheme: Q,K and S computed with split bf16 (hi+lo, 3 MFMA
// products -> ~2^-17 relative error) because softmax is near-one-hot with
// huge score variance; V / PV in plain bf16.
// ---------------------------------------------------------------------------

#define S1N 4096
#define S2N 4096
#define DIN 1024

using f32x4  = __attribute__((ext_vector_type(4))) float;
using bf16x8 = __attribute__((ext_vector_type(8))) __bf16;
using u16    = unsigned short;
using u16x4  = __attribute__((ext_vector_type(4))) unsigned short;
using u16x8  = __attribute__((ext_vector_type(8))) unsigned short;

__device__ __forceinline__ u16 f2bf(float f) {
    unsigned u = __float_as_uint(f);
    u += 0x7fffu + ((u >> 16) & 1u);        // RNE
    return (u16)(u >> 16);
}
__device__ __forceinline__ float bf2f(u16 h) {
    return __uint_as_float(((unsigned)h) << 16);
}

__device__ __forceinline__ void gload16(const void* g, void* l) {
    __builtin_amdgcn_global_load_lds(
        (const __attribute__((address_space(1))) void*)g,
        (__attribute__((address_space(3))) void*)l, 16, 0, 0);
}

// ---------------------------------------------------------------------------
// split conversion: x (f32) -> xh + xl (bf16 pair)
__global__ __launch_bounds__(256) void split_cvt(const float* __restrict__ x,
                                                 u16* __restrict__ xh,
                                                 u16* __restrict__ xl, int n4) {
    int i = blockIdx.x * 256 + threadIdx.x;
    if (i >= n4) return;
    f32x4 v = *(const f32x4*)&x[(size_t)i * 4];
    u16x4 h, l;
#pragma unroll
    for (int j = 0; j < 4; ++j) {
        h[j] = f2bf(v[j]);
        l[j] = f2bf(v[j] - bf2f(h[j]));
    }
    *(u16x4*)&xh[(size_t)i * 4] = h;
    *(u16x4*)&xl[(size_t)i * 4] = l;
}

// transpose + split: W [1024(K)][1024(N)] f32 -> Wt hi/lo [N][K] bf16
__global__ __launch_bounds__(256) void wsplitT(const float* __restrict__ W,
                                               u16* __restrict__ Wht,
                                               u16* __restrict__ Wlt) {
    __shared__ float tile[64][65];
    const int n0 = blockIdx.x * 64, k0 = blockIdx.y * 64;
    const int tx = threadIdx.x & 63, tg = threadIdx.x >> 6;
#pragma unroll
    for (int i = 0; i < 16; ++i)
        tile[tg + i * 4][tx] = W[(size_t)(k0 + tg + i * 4) * DIN + n0 + tx];
    __syncthreads();
#pragma unroll
    for (int i = 0; i < 16; ++i) {
        int r = tg + i * 4;
        float v = tile[tx][r];
        u16 h = f2bf(v);
        Wht[(size_t)(n0 + r) * DIN + k0 + tx] = h;
        Wlt[(size_t)(n0 + r) * DIN + k0 + tx] = f2bf(v - bf2f(h));
    }
}

// ---------------------------------------------------------------------------
// GEMM: C[M,N] = A[M,K] * Bt[N,K]^T, bf16 inputs, f32 accumulate.
// SPLIT: A,Bt given as hi/lo pairs; acc += Ah*Bh + Ah*Bl + Al*Bh.
// EPI: 0 = f32 out, 1 = split bf16 out (hi C0, lo C1), 2 = bf16 transposed out
// 128x128 tile, BK=32, 4 waves (each 64x64 via 4x4 frags of 16x16x32 MFMA).
template <int SPLIT, int EPI>
__global__ __launch_bounds__(256) void gemm_bt(
    const u16* __restrict__ Ah, const u16* __restrict__ Al,
    const u16* __restrict__ Bh, const u16* __restrict__ Bl,
    void* __restrict__ C0, void* __restrict__ C1,
    int M, int N, int K, float scale) {
    extern __shared__ u16 lds[];
    u16* Ash = lds;             // [128][32]
    u16* Bsh = lds + 4096;
    u16* Asl = lds + 8192;      // used only when SPLIT
    u16* Bsl = lds + 12288;

    const int tid  = threadIdx.x;
    const int wave = tid >> 6;
    const int lane = tid & 63;
    const int brow = blockIdx.x * 128;
    const int bcol = blockIdx.y * 128;
    const int wr = wave >> 1, wc = wave & 1;
    const int fr = lane & 15, fq = lane >> 4;

    f32x4 acc[4][4] = {};

    const int srow = wave * 32 + (lane >> 2);   // staging row in tile
    const int scol = (lane & 3) * 8;            // staging col (ushort)

    for (int k0 = 0; k0 < K; k0 += 32) {
        const size_t aoff = (size_t)(brow + srow) * K + k0 + scol;
        const size_t boff = (size_t)(bcol + srow) * K + k0 + scol;
        u16* la = Ash + wave * 1024;            // wave-uniform LDS dest
        u16* lb = Bsh + wave * 1024;
        gload16(Ah + aoff, la);
        gload16(Ah + aoff + (size_t)16 * K, la + 512);
        gload16(Bh + boff, lb);
        gload16(Bh + boff + (size_t)16 * K, lb + 512);
        if (SPLIT) {
            u16* la2 = Asl + wave * 1024;
            u16* lb2 = Bsl + wave * 1024;
            gload16(Al + aoff, la2);
            gload16(Al + aoff + (size_t)16 * K, la2 + 512);
            gload16(Bl + boff, lb2);
            gload16(Bl + boff + (size_t)16 * K, lb2 + 512);
        }
        __syncthreads();

        bf16x8 af[4], bg[4], afl[4], bgl[4];
#pragma unroll
        for (int m = 0; m < 4; ++m)
            af[m] = *(const bf16x8*)&Ash[(wr * 64 + m * 16 + fr) * 32 + fq * 8];
#pragma unroll
        for (int n = 0; n < 4; ++n)
            bg[n] = *(const bf16x8*)&Bsh[(wc * 64 + n * 16 + fr) * 32 + fq * 8];
        if (SPLIT) {
#pragma unroll
            for (int m = 0; m < 4; ++m)
                afl[m] = *(const bf16x8*)&Asl[(wr * 64 + m * 16 + fr) * 32 + fq * 8];
#pragma unroll
            for (int n = 0; n < 4; ++n)
                bgl[n] = *(const bf16x8*)&Bsl[(wc * 64 + n * 16 + fr) * 32 + fq * 8];
        }
#pragma unroll
        for (int m = 0; m < 4; ++m)
#pragma unroll
            for (int n = 0; n < 4; ++n) {
                acc[m][n] = __builtin_amdgcn_mfma_f32_16x16x32_bf16(
                    af[m], bg[n], acc[m][n], 0, 0, 0);
                if (SPLIT) {
                    acc[m][n] = __builtin_amdgcn_mfma_f32_16x16x32_bf16(
                        af[m], bgl[n], acc[m][n], 0, 0, 0);
                    acc[m][n] = __builtin_amdgcn_mfma_f32_16x16x32_bf16(
                        afl[m], bg[n], acc[m][n], 0, 0, 0);
                }
            }
        __syncthreads();
    }

#pragma unroll
    for (int m = 0; m < 4; ++m)
#pragma unroll
        for (int n = 0; n < 4; ++n)
#pragma unroll
            for (int r = 0; r < 4; ++r) {
                int row = brow + wr * 64 + m * 16 + fq * 4 + r;
                int col = bcol + wc * 64 + n * 16 + fr;
                float v = acc[m][n][r] * scale;
                if (EPI == 0) {
                    ((float*)C0)[(size_t)row * N + col] = v;
                } else if (EPI == 1) {
                    u16 h = f2bf(v);
                    ((u16*)C0)[(size_t)row * N + col] = h;
                    ((u16*)C1)[(size_t)row * N + col] = f2bf(v - bf2f(h));
                } else {
                    ((u16*)C0)[(size_t)col * M + row] = f2bf(v);  // transposed
                }
            }
}

// ---------------------------------------------------------------------------
// row softmax: P[row] = softmax(S[row] * scale), written as bf16.
// c = scale * log2(e); one block per row, 16 f32 per thread held in regs.
__global__ __launch_bounds__(256) void softmax_rows(const float* __restrict__ S,
                                                    u16* __restrict__ P, float c) {
    const int row = blockIdx.x;
    const float* s = S + (size_t)row * S2N;
    const int t = threadIdx.x;
    f32x4 v[4];
#pragma unroll
    for (int j = 0; j < 4; ++j) v[j] = *(const f32x4*)&s[t * 16 + j * 4];

    float mx = -3.4e38f;
#pragma unroll
    for (int j = 0; j < 4; ++j)
#pragma unroll
        for (int e = 0; e < 4; ++e) mx = fmaxf(mx, v[j][e]);
#pragma unroll
    for (int off = 32; off; off >>= 1) mx = fmaxf(mx, __shfl_xor(mx, off));
    __shared__ float redm[4], reds[4];
    if ((t & 63) == 0) redm[t >> 6] = mx;
    __syncthreads();
    mx = fmaxf(fmaxf(redm[0], redm[1]), fmaxf(redm[2], redm[3]));

    float sum = 0.f;
#pragma unroll
    for (int j = 0; j < 4; ++j)
#pragma unroll
        for (int e = 0; e < 4; ++e) {
            float ex = exp2f((v[j][e] - mx) * c);
            v[j][e] = ex;
            sum += ex;
        }
#pragma unroll
    for (int off = 32; off; off >>= 1) sum += __shfl_xor(sum, off);
    if ((t & 63) == 0) reds[t >> 6] = sum;
    __syncthreads();
    sum = (reds[0] + reds[1]) + (reds[2] + reds[3]);
    float rs = 1.0f / sum;

    u16x8 o0, o1;
#pragma unroll
    for (int j = 0; j < 4; ++j)
#pragma unroll
        for (int e = 0; e < 4; ++e) {
            int idx = j * 4 + e;
            u16 b = f2bf(v[j][e] * rs);
            if (idx < 8) o0[idx] = b; else o1[idx - 8] = b;
        }
    *(u16x8*)&P[(size_t)row * S2N + t * 16] = o0;
    *(u16x8*)&P[(size_t)row * S2N + t * 16 + 8] = o1;
}

// ---------------------------------------------------------------------------
extern "C" void kernel_launch(void* const* d_in, const int* in_sizes, int n_in,
                              void* d_out, int out_size, void* d_ws, size_t ws_size,
                              hipStream_t stream) {
    const float* x1 = (const float*)d_in[0];
    const float* x2 = (const float*)d_in[1];
    const float* Wq = (const float*)d_in[2];
    const float* Wk = (const float*)d_in[3];
    const float* Wv = (const float*)d_in[4];

    char* ws = (char*)d_ws;
    const size_t MB = 1024 * 1024;
    // live ranges: [Qh..Kl | Vt | cvt-region] ; S overlaps cvt-region (dead
    // after V-GEMM); P overlaps Qh..Kl (dead after S-GEMM). Total 104 MB.
    u16* Qh  = (u16*)(ws + 0 * MB);
    u16* Ql  = (u16*)(ws + 8 * MB);
    u16* Kh  = (u16*)(ws + 16 * MB);
    u16* Kl  = (u16*)(ws + 24 * MB);
    u16* Vt  = (u16*)(ws + 32 * MB);
    u16* x1h = (u16*)(ws + 40 * MB);
    u16* x1l = (u16*)(ws + 48 * MB);
    u16* x2h = (u16*)(ws + 56 * MB);
    u16* x2l = (u16*)(ws + 64 * MB);
    u16* Wqh = (u16*)(ws + 72 * MB);
    u16* Wql = (u16*)(ws + 74 * MB);
    u16* Wkh = (u16*)(ws + 76 * MB);
    u16* Wkl = (u16*)(ws + 78 * MB);
    u16* Wvh = (u16*)(ws + 80 * MB);
    u16* Wvl = (u16*)(ws + 82 * MB);
    float* Smat = (float*)(ws + 40 * MB);   // 64 MB, reuses cvt region
    u16* P   = (u16*)(ws + 0 * MB);         // 32 MB, reuses Q/K region

    // conversions
    split_cvt<<<4096, 256, 0, stream>>>(x1, x1h, x1l, 1048576);
    split_cvt<<<4096, 256, 0, stream>>>(x2, x2h, x2l, 1048576);
    wsplitT<<<dim3(16, 16), 256, 0, stream>>>(Wq, Wqh, Wql);
    wsplitT<<<dim3(16, 16), 256, 0, stream>>>(Wk, Wkh, Wkl);
    wsplitT<<<dim3(16, 16), 256, 0, stream>>>(Wv, Wvh, Wvl);

    // projections: Q, K split-precision; V plain bf16 written transposed
    gemm_bt<1, 1><<<dim3(32, 8), 256, 32768, stream>>>(
        x1h, x1l, Wqh, Wql, Qh, Ql, S1N, 1024, DIN, 1.0f);
    gemm_bt<1, 1><<<dim3(32, 8), 256, 32768, stream>>>(
        x2h, x2l, Wkh, Wkl, Kh, Kl, S2N, 1024, DIN, 1.0f);
    gemm_bt<0, 2><<<dim3(32, 8), 256, 16384, stream>>>(
        x2h, nullptr, Wvh, nullptr, Vt, nullptr, S2N, 1024, DIN, 1.0f);

    // scores S = Q K^T (split precision, f32 out)
    gemm_bt<1, 0><<<dim3(32, 32), 256, 32768, stream>>>(
        Qh, Ql, Kh, Kl, Smat, nullptr, S1N, S2N, 1024, 1.0f);

    // softmax(S/32) -> P (bf16);  c = (1/32) * log2(e)
    softmax_rows<<<4096, 256, 0, stream>>>(Smat, P, 0.04508422002778011f);

    // O = P V
    gemm_bt<0, 0><<<dim3(32, 8), 256, 16384, stream>>>(
        P, nullptr, Vt, nullptr, d_out, nullptr, S1N, 1024, S2N, 1.0f);
}

// Round 2
// 324.821 us; speedup vs baseline: 1.1080x; 1.1080x over previous
//
#include <hip/hip_runtime.h>

// ---------------------------------------------------------------------------
// CrossAttention: O = softmax((x1 Wq)(x2 Wk)^T / 32) (x2 Wv)
// S1=S2=4096, D_IN=D_KQ=D_V=1024, fp32 in/out.
// Split-bf16 (hi+lo, 3 MFMA products) for Q,K,S; plain bf16 for V,PV.
// Round 2: S-GEMM moved to a 256x256 counted-vmcnt phase pipeline
// (T2 swizzle + T3/T4 phases + T5 setprio).
// ---------------------------------------------------------------------------

#define S1N 4096
#define S2N 4096
#define DIN 1024

using f32x4  = __attribute__((ext_vector_type(4))) float;
using bf16x8 = __attribute__((ext_vector_type(8))) __bf16;
using u16    = unsigned short;
using u16x4  = __attribute__((ext_vector_type(4))) unsigned short;
using u16x8  = __attribute__((ext_vector_type(8))) unsigned short;

__device__ __forceinline__ u16 f2bf(float f) {
    unsigned u = __float_as_uint(f);
    u += 0x7fffu + ((u >> 16) & 1u);        // RNE
    return (u16)(u >> 16);
}
__device__ __forceinline__ float bf2f(u16 h) {
    return __uint_as_float(((unsigned)h) << 16);
}

__device__ __forceinline__ void gload16(const void* g, void* l) {
    __builtin_amdgcn_global_load_lds(
        (const __attribute__((address_space(1))) void*)g,
        (__attribute__((address_space(3))) void*)l, 16, 0, 0);
}

#define WAIT_VM(N) asm volatile("s_waitcnt vmcnt(" #N ")" ::: "memory")
#define LGKM0()    asm volatile("s_waitcnt lgkmcnt(0)" ::: "memory")
#define FENCE()    asm volatile("" ::: "memory")

// ---------------------------------------------------------------------------
// split conversion: x (f32) -> xh + xl (bf16 pair)
__global__ __launch_bounds__(256) void split_cvt(const float* __restrict__ x,
                                                 u16* __restrict__ xh,
                                                 u16* __restrict__ xl, int n4) {
    int i = blockIdx.x * 256 + threadIdx.x;
    if (i >= n4) return;
    f32x4 v = *(const f32x4*)&x[(size_t)i * 4];
    u16x4 h, l;
#pragma unroll
    for (int j = 0; j < 4; ++j) {
        h[j] = f2bf(v[j]);
        l[j] = f2bf(v[j] - bf2f(h[j]));
    }
    *(u16x4*)&xh[(size_t)i * 4] = h;
    *(u16x4*)&xl[(size_t)i * 4] = l;
}

// transpose + split: W [1024(K)][1024(N)] f32 -> Wt hi/lo [N][K] bf16
__global__ __launch_bounds__(256) void wsplitT(const float* __restrict__ W,
                                               u16* __restrict__ Wht,
                                               u16* __restrict__ Wlt) {
    __shared__ float tile[64][65];
    const int n0 = blockIdx.x * 64, k0 = blockIdx.y * 64;
    const int tx = threadIdx.x & 63, tg = threadIdx.x >> 6;
#pragma unroll
    for (int i = 0; i < 16; ++i)
        tile[tg + i * 4][tx] = W[(size_t)(k0 + tg + i * 4) * DIN + n0 + tx];
    __syncthreads();
#pragma unroll
    for (int i = 0; i < 16; ++i) {
        int r = tg + i * 4;
        float v = tile[tx][r];
        u16 h = f2bf(v);
        Wht[(size_t)(n0 + r) * DIN + k0 + tx] = h;
        Wlt[(size_t)(n0 + r) * DIN + k0 + tx] = f2bf(v - bf2f(h));
    }
}

// ---------------------------------------------------------------------------
// m97-structure GEMM kept for projections / V / PV.
// C[M,N] = A[M,K] * Bt[N,K]^T, bf16 in, f32 acc.
// EPI: 0 = f32 out, 1 = split bf16 out (hi C0, lo C1), 2 = bf16 transposed out
template <int SPLIT, int EPI>
__global__ __launch_bounds__(256) void gemm_bt(
    const u16* __restrict__ Ah, const u16* __restrict__ Al,
    const u16* __restrict__ Bh, const u16* __restrict__ Bl,
    void* __restrict__ C0, void* __restrict__ C1,
    int M, int N, int K, float scale) {
    extern __shared__ u16 lds[];
    u16* Ash = lds;             // [128][32]
    u16* Bsh = lds + 4096;
    u16* Asl = lds + 8192;      // used only when SPLIT
    u16* Bsl = lds + 12288;

    const int tid  = threadIdx.x;
    const int wave = tid >> 6;
    const int lane = tid & 63;
    const int brow = blockIdx.x * 128;
    const int bcol = blockIdx.y * 128;
    const int wr = wave >> 1, wc = wave & 1;
    const int fr = lane & 15, fq = lane >> 4;

    f32x4 acc[4][4] = {};

    const int srow = wave * 32 + (lane >> 2);   // staging row in tile
    const int scol = (lane & 3) * 8;            // staging col (ushort)

    for (int k0 = 0; k0 < K; k0 += 32) {
        const size_t aoff = (size_t)(brow + srow) * K + k0 + scol;
        const size_t boff = (size_t)(bcol + srow) * K + k0 + scol;
        u16* la = Ash + wave * 1024;            // wave-uniform LDS dest
        u16* lb = Bsh + wave * 1024;
        gload16(Ah + aoff, la);
        gload16(Ah + aoff + (size_t)16 * K, la + 512);
        gload16(Bh + boff, lb);
        gload16(Bh + boff + (size_t)16 * K, lb + 512);
        if (SPLIT) {
            u16* la2 = Asl + wave * 1024;
            u16* lb2 = Bsl + wave * 1024;
            gload16(Al + aoff, la2);
            gload16(Al + aoff + (size_t)16 * K, la2 + 512);
            gload16(Bl + boff, lb2);
            gload16(Bl + boff + (size_t)16 * K, lb2 + 512);
        }
        __syncthreads();

        bf16x8 af[4], bg[4], afl[4], bgl[4];
#pragma unroll
        for (int m = 0; m < 4; ++m)
            af[m] = *(const bf16x8*)&Ash[(wr * 64 + m * 16 + fr) * 32 + fq * 8];
#pragma unroll
        for (int n = 0; n < 4; ++n)
            bg[n] = *(const bf16x8*)&Bsh[(wc * 64 + n * 16 + fr) * 32 + fq * 8];
        if (SPLIT) {
#pragma unroll
            for (int m = 0; m < 4; ++m)
                afl[m] = *(const bf16x8*)&Asl[(wr * 64 + m * 16 + fr) * 32 + fq * 8];
#pragma unroll
            for (int n = 0; n < 4; ++n)
                bgl[n] = *(const bf16x8*)&Bsl[(wc * 64 + n * 16 + fr) * 32 + fq * 8];
        }
#pragma unroll
        for (int m = 0; m < 4; ++m)
#pragma unroll
            for (int n = 0; n < 4; ++n) {
                acc[m][n] = __builtin_amdgcn_mfma_f32_16x16x32_bf16(
                    af[m], bg[n], acc[m][n], 0, 0, 0);
                if (SPLIT) {
                    acc[m][n] = __builtin_amdgcn_mfma_f32_16x16x32_bf16(
                        af[m], bgl[n], acc[m][n], 0, 0, 0);
                    acc[m][n] = __builtin_amdgcn_mfma_f32_16x16x32_bf16(
                        afl[m], bg[n], acc[m][n], 0, 0, 0);
                }
            }
        __syncthreads();
    }

#pragma unroll
    for (int m = 0; m < 4; ++m)
#pragma unroll
        for (int n = 0; n < 4; ++n)
#pragma unroll
            for (int r = 0; r < 4; ++r) {
                int row = brow + wr * 64 + m * 16 + fq * 4 + r;
                int col = bcol + wc * 64 + n * 16 + fr;
                float v = acc[m][n][r] * scale;
                if (EPI == 0) {
                    ((float*)C0)[(size_t)row * N + col] = v;
                } else if (EPI == 1) {
                    u16 h = f2bf(v);
                    ((u16*)C0)[(size_t)row * N + col] = h;
                    ((u16*)C1)[(size_t)row * N + col] = f2bf(v - bf2f(h));
                } else {
                    ((u16*)C0)[(size_t)col * M + row] = f2bf(v);  // transposed
                }
            }
}

// ---------------------------------------------------------------------------
// Pipelined split S-GEMM: S[4096,4096] = Q K^T, hi/lo bf16 split, f32 out.
// BM=BN=256, BK=32, 512 threads (8 waves, 2x4), per-wave 128x64 out.
// LDS: 2 x 64KB buffers, each {Ah,Al,Bh,Bl} of 256x32 u16 (16KB each).
// Per K-tile 3 phases (one per split product); counted vmcnt(4)/(6)/(6)
// keeps 8 loads in flight across barriers. 16B-slot XOR swizzle
// (slot ^= (row>>1)&3) applied on pre-swizzled global source + ds_read.
__global__ __launch_bounds__(512, 2) void gemm_s_pipe(
    const u16* __restrict__ QH, const u16* __restrict__ QL,
    const u16* __restrict__ KH, const u16* __restrict__ KL,
    float* __restrict__ S) {
    extern __shared__ u16 lds[];
    // unit offsets within a 32768-u16 buffer:
    //   AH: 0   AL: 8192   BH: 16384   BL: 24576

    const int tid  = threadIdx.x;
    const int wave = tid >> 6;
    const int lane = tid & 63;
    const int brow = blockIdx.x * 256;
    const int bcol = blockIdx.y * 256;
    const int wr = wave >> 2;          // 0..1 -> rows wr*128
    const int wc = wave & 3;           // 0..3 -> cols wc*64
    const int fr = lane & 15, fq = lane >> 4;
    const int sl = fq ^ ((fr >> 1) & 3);              // swizzled 16B slot
    const int aoff = (wr * 128 + fr) * 32 + sl * 8;   // u16 offset, frag m adds m*512
    const int boff = (wc * 64 + fr) * 32 + sl * 8;    // frag n adds n*512
    const int wb = wave * 512;                        // wave-uniform stage base (u16)

    f32x4 acc[8][4] = {};

    // stage one 256x32 unit of matrix g (row-major, ld=1024) for k-tile at k0
    // into LDS unit lu. Source slot pre-swizzled so linear LDS dest ends up
    // swizzled: LDS[row][s'] = G[row][s' ^ ((row>>1)&3)].
    auto stage256 = [&](const u16* __restrict__ g, int grow0, int k0, u16* lu) {
#pragma unroll
        for (int j = 0; j < 2; ++j) {
            const int idx = j * 512 + tid;
            const int row = idx >> 2;
            const int gs  = (idx & 3) ^ ((row >> 1) & 3);
            gload16(g + (size_t)(grow0 + row) * 1024 + k0 + gs * 8,
                    lu + j * 4096 + wb);
        }
    };

    // prologue: tile 0 into buf0, in consumption order AH,BH,BL,AL (8 loads)
    stage256(QH, brow, 0, lds + 0);
    stage256(KH, bcol, 0, lds + 16384);
    stage256(KL, bcol, 0, lds + 24576);
    stage256(QL, brow, 0, lds + 8192);

    for (int t = 0; t < 32; ++t) {
        u16* cur = lds + (t & 1) * 32768;
        u16* nxt = lds + ((t + 1) & 1) * 32768;
        const int k1 = (t < 31 ? t + 1 : 31) * 32;   // clamp: last tile re-stages

        bf16x8 ah[8], al[8], bh[4], bl[4];

        // ---- phase 0: Ah x Bh  (needs AH[t], BH[t] = oldest 4 loads)
        WAIT_VM(4);
        __builtin_amdgcn_s_barrier();
        FENCE();
        stage256(QH, brow, k1, nxt + 0);
        stage256(KH, bcol, k1, nxt + 16384);
#pragma unroll
        for (int m = 0; m < 8; ++m)
            ah[m] = *(const bf16x8*)&cur[aoff + m * 512];
#pragma unroll
        for (int n = 0; n < 4; ++n)
            bh[n] = *(const bf16x8*)&cur[16384 + boff + n * 512];
        LGKM0();
        __builtin_amdgcn_sched_barrier(0);
        __builtin_amdgcn_s_setprio(1);
#pragma unroll
        for (int m = 0; m < 8; ++m)
#pragma unroll
            for (int n = 0; n < 4; ++n)
                acc[m][n] = __builtin_amdgcn_mfma_f32_16x16x32_bf16(
                    ah[m], bh[n], acc[m][n], 0, 0, 0);
        __builtin_amdgcn_s_setprio(0);

        // ---- phase 1: Ah x Bl  (needs BL[t] = oldest 2 of 8 outstanding)
        WAIT_VM(6);
        __builtin_amdgcn_s_barrier();
        FENCE();
        stage256(KL, bcol, k1, nxt + 24576);
#pragma unroll
        for (int n = 0; n < 4; ++n)
            bl[n] = *(const bf16x8*)&cur[24576 + boff + n * 512];
        LGKM0();
        __builtin_amdgcn_sched_barrier(0);
        __builtin_amdgcn_s_setprio(1);
#pragma unroll
        for (int m = 0; m < 8; ++m)
#pragma unroll
            for (int n = 0; n < 4; ++n)
                acc[m][n] = __builtin_amdgcn_mfma_f32_16x16x32_bf16(
                    ah[m], bl[n], acc[m][n], 0, 0, 0);
        __builtin_amdgcn_s_setprio(0);

        // ---- phase 2: Al x Bh  (needs AL[t] = oldest 2 of 8 outstanding)
        WAIT_VM(6);
        __builtin_amdgcn_s_barrier();
        FENCE();
        stage256(QL, brow, k1, nxt + 8192);
#pragma unroll
        for (int m = 0; m < 8; ++m)
            al[m] = *(const bf16x8*)&cur[8192 + aoff + m * 512];
        LGKM0();
        __builtin_amdgcn_sched_barrier(0);
        __builtin_amdgcn_s_setprio(1);
#pragma unroll
        for (int m = 0; m < 8; ++m)
#pragma unroll
            for (int n = 0; n < 4; ++n)
                acc[m][n] = __builtin_amdgcn_mfma_f32_16x16x32_bf16(
                    al[m], bh[n], acc[m][n], 0, 0, 0);
        __builtin_amdgcn_s_setprio(0);
    }
    asm volatile("s_waitcnt vmcnt(0)" ::: "memory");  // drain before endpgm

    // epilogue: C-layout row=(lane>>4)*4+reg, col=lane&15 per 16x16 frag
#pragma unroll
    for (int m = 0; m < 8; ++m)
#pragma unroll
        for (int n = 0; n < 4; ++n)
#pragma unroll
            for (int r = 0; r < 4; ++r) {
                int row = brow + wr * 128 + m * 16 + fq * 4 + r;
                int col = bcol + wc * 64 + n * 16 + fr;
                S[(size_t)row * S2N + col] = acc[m][n][r];
            }
}

// ---------------------------------------------------------------------------
// row softmax: P[row] = softmax(S[row] * scale), written as bf16.
__global__ __launch_bounds__(256) void softmax_rows(const float* __restrict__ S,
                                                    u16* __restrict__ P, float c) {
    const int row = blockIdx.x;
    const float* s = S + (size_t)row * S2N;
    const int t = threadIdx.x;
    f32x4 v[4];
#pragma unroll
    for (int j = 0; j < 4; ++j) v[j] = *(const f32x4*)&s[t * 16 + j * 4];

    float mx = -3.4e38f;
#pragma unroll
    for (int j = 0; j < 4; ++j)
#pragma unroll
        for (int e = 0; e < 4; ++e) mx = fmaxf(mx, v[j][e]);
#pragma unroll
    for (int off = 32; off; off >>= 1) mx = fmaxf(mx, __shfl_xor(mx, off));
    __shared__ float redm[4], reds[4];
    if ((t & 63) == 0) redm[t >> 6] = mx;
    __syncthreads();
    mx = fmaxf(fmaxf(redm[0], redm[1]), fmaxf(redm[2], redm[3]));

    float sum = 0.f;
#pragma unroll
    for (int j = 0; j < 4; ++j)
#pragma unroll
        for (int e = 0; e < 4; ++e) {
            float ex = exp2f((v[j][e] - mx) * c);
            v[j][e] = ex;
            sum += ex;
        }
#pragma unroll
    for (int off = 32; off; off >>= 1) sum += __shfl_xor(sum, off);
    if ((t & 63) == 0) reds[t >> 6] = sum;
    __syncthreads();
    sum = (reds[0] + reds[1]) + (reds[2] + reds[3]);
    float rs = 1.0f / sum;

    u16x8 o0, o1;
#pragma unroll
    for (int j = 0; j < 4; ++j)
#pragma unroll
        for (int e = 0; e < 4; ++e) {
            int idx = j * 4 + e;
            u16 b = f2bf(v[j][e] * rs);
            if (idx < 8) o0[idx] = b; else o1[idx - 8] = b;
        }
    *(u16x8*)&P[(size_t)row * S2N + t * 16] = o0;
    *(u16x8*)&P[(size_t)row * S2N + t * 16 + 8] = o1;
}

// ---------------------------------------------------------------------------
extern "C" void kernel_launch(void* const* d_in, const int* in_sizes, int n_in,
                              void* d_out, int out_size, void* d_ws, size_t ws_size,
                              hipStream_t stream) {
    const float* x1 = (const float*)d_in[0];
    const float* x2 = (const float*)d_in[1];
    const float* Wq = (const float*)d_in[2];
    const float* Wk = (const float*)d_in[3];
    const float* Wv = (const float*)d_in[4];

    char* ws = (char*)d_ws;
    const size_t MB = 1024 * 1024;
    u16* Qh  = (u16*)(ws + 0 * MB);
    u16* Ql  = (u16*)(ws + 8 * MB);
    u16* Kh  = (u16*)(ws + 16 * MB);
    u16* Kl  = (u16*)(ws + 24 * MB);
    u16* Vt  = (u16*)(ws + 32 * MB);
    u16* x1h = (u16*)(ws + 40 * MB);
    u16* x1l = (u16*)(ws + 48 * MB);
    u16* x2h = (u16*)(ws + 56 * MB);
    u16* x2l = (u16*)(ws + 64 * MB);
    u16* Wqh = (u16*)(ws + 72 * MB);
    u16* Wql = (u16*)(ws + 74 * MB);
    u16* Wkh = (u16*)(ws + 76 * MB);
    u16* Wkl = (u16*)(ws + 78 * MB);
    u16* Wvh = (u16*)(ws + 80 * MB);
    u16* Wvl = (u16*)(ws + 82 * MB);
    float* Smat = (float*)(ws + 40 * MB);   // 64 MB, reuses cvt region
    u16* P   = (u16*)(ws + 0 * MB);         // 32 MB, reuses Q/K region

    // conversions
    split_cvt<<<4096, 256, 0, stream>>>(x1, x1h, x1l, 1048576);
    split_cvt<<<4096, 256, 0, stream>>>(x2, x2h, x2l, 1048576);
    wsplitT<<<dim3(16, 16), 256, 0, stream>>>(Wq, Wqh, Wql);
    wsplitT<<<dim3(16, 16), 256, 0, stream>>>(Wk, Wkh, Wkl);
    wsplitT<<<dim3(16, 16), 256, 0, stream>>>(Wv, Wvh, Wvl);

    // projections: Q, K split-precision; V plain bf16 written transposed
    gemm_bt<1, 1><<<dim3(32, 8), 256, 32768, stream>>>(
        x1h, x1l, Wqh, Wql, Qh, Ql, S1N, 1024, DIN, 1.0f);
    gemm_bt<1, 1><<<dim3(32, 8), 256, 32768, stream>>>(
        x2h, x2l, Wkh, Wkl, Kh, Kl, S2N, 1024, DIN, 1.0f);
    gemm_bt<0, 2><<<dim3(32, 8), 256, 16384, stream>>>(
        x2h, nullptr, Wvh, nullptr, Vt, nullptr, S2N, 1024, DIN, 1.0f);

    // scores S = Q K^T (split precision, f32 out) — pipelined 256x256 kernel
    gemm_s_pipe<<<dim3(16, 16), 512, 131072, stream>>>(Qh, Ql, Kh, Kl, Smat);

    // softmax(S/32) -> P (bf16);  c = (1/32) * log2(e)
    softmax_rows<<<4096, 256, 0, stream>>>(Smat, P, 0.04508422002778011f);

    // O = P V
    gemm_bt<0, 0><<<dim3(32, 8), 256, 16384, stream>>>(
        P, nullptr, Vt, nullptr, d_out, nullptr, S1N, 1024, S2N, 1.0f);
}

// Round 3
// 256.489 us; speedup vs baseline: 1.4031x; 1.2664x over previous
//
#include <hip/hip_runtime.h>

// ---------------------------------------------------------------------------
// CrossAttention: O = softmax((x1 Wq)(x2 Wk)^T / 32) (x2 Wv)
// S1=S2=4096, D_IN=D_KQ=D_V=1024, fp32 in/out.
// Split-bf16 (hi+lo, 3 MFMA products) for Q,K,S; plain bf16 for V,PV.
// Round 3: occupancy fixes — fused QKV projection dispatch (z-indexed),
// PV split-K4 in one dispatch + add pass, fused conversions.
// ---------------------------------------------------------------------------

#define S1N 4096
#define S2N 4096
#define DIN 1024

using f32x4  = __attribute__((ext_vector_type(4))) float;
using bf16x8 = __attribute__((ext_vector_type(8))) __bf16;
using u16    = unsigned short;
using u16x4  = __attribute__((ext_vector_type(4))) unsigned short;
using u16x8  = __attribute__((ext_vector_type(8))) unsigned short;

__device__ __forceinline__ u16 f2bf(float f) {
    unsigned u = __float_as_uint(f);
    u += 0x7fffu + ((u >> 16) & 1u);        // RNE
    return (u16)(u >> 16);
}
__device__ __forceinline__ float bf2f(u16 h) {
    return __uint_as_float(((unsigned)h) << 16);
}

__device__ __forceinline__ void gload16(const void* g, void* l) {
    __builtin_amdgcn_global_load_lds(
        (const __attribute__((address_space(1))) void*)g,
        (__attribute__((address_space(3))) void*)l, 16, 0, 0);
}

#define WAIT_VM(N) asm volatile("s_waitcnt vmcnt(" #N ")" ::: "memory")
#define LGKM0()    asm volatile("s_waitcnt lgkmcnt(0)" ::: "memory")
#define FENCE()    asm volatile("" ::: "memory")

// ---------------------------------------------------------------------------
// fused split conversion: x1,x2 (f32) -> hi/lo bf16 pairs, one dispatch
__global__ __launch_bounds__(256) void split_cvt2(
    const float* __restrict__ x1, u16* __restrict__ x1h, u16* __restrict__ x1l,
    const float* __restrict__ x2, u16* __restrict__ x2h, u16* __restrict__ x2l) {
    int b = blockIdx.x;
    const float* x; u16 *xh, *xl;
    if (b < 4096) { x = x1; xh = x1h; xl = x1l; }
    else          { x = x2; xh = x2h; xl = x2l; b -= 4096; }
    int i = b * 256 + threadIdx.x;
    f32x4 v = *(const f32x4*)&x[(size_t)i * 4];
    u16x4 h, l;
#pragma unroll
    for (int j = 0; j < 4; ++j) {
        h[j] = f2bf(v[j]);
        l[j] = f2bf(v[j] - bf2f(h[j]));
    }
    *(u16x4*)&xh[(size_t)i * 4] = h;
    *(u16x4*)&xl[(size_t)i * 4] = l;
}

// fused transpose+split for Wq/Wk/Wv (z selects): W[K][N] f32 -> Wt hi/lo [N][K]
__global__ __launch_bounds__(256) void wsplitT3(
    const float* __restrict__ Wq, u16* __restrict__ Wqh, u16* __restrict__ Wql,
    const float* __restrict__ Wk, u16* __restrict__ Wkh, u16* __restrict__ Wkl,
    const float* __restrict__ Wv, u16* __restrict__ Wvh, u16* __restrict__ Wvl) {
    const float* W; u16 *Wht, *Wlt;
    if (blockIdx.z == 0)      { W = Wq; Wht = Wqh; Wlt = Wql; }
    else if (blockIdx.z == 1) { W = Wk; Wht = Wkh; Wlt = Wkl; }
    else                      { W = Wv; Wht = Wvh; Wlt = Wvl; }
    __shared__ float tile[64][65];
    const int n0 = blockIdx.x * 64, k0 = blockIdx.y * 64;
    const int tx = threadIdx.x & 63, tg = threadIdx.x >> 6;
#pragma unroll
    for (int i = 0; i < 16; ++i)
        tile[tg + i * 4][tx] = W[(size_t)(k0 + tg + i * 4) * DIN + n0 + tx];
    __syncthreads();
#pragma unroll
    for (int i = 0; i < 16; ++i) {
        int r = tg + i * 4;
        float v = tile[tx][r];
        u16 h = f2bf(v);
        Wht[(size_t)(n0 + r) * DIN + k0 + tx] = h;
        Wlt[(size_t)(n0 + r) * DIN + k0 + tx] = f2bf(v - bf2f(h));
    }
}

// ---------------------------------------------------------------------------
// m97-structure GEMM body (device fn). C[M,N] = A[M,K] * Bt[N,K]^T over
// k in [kbeg,kend); K is also the row stride of A and Bt.
// EPI: 0 = f32 out, 1 = split bf16 out (hi C0, lo C1), 2 = bf16 transposed out
template <int SPLIT, int EPI>
__device__ __forceinline__ void gemm_bt_body(
    const u16* __restrict__ Ah, const u16* __restrict__ Al,
    const u16* __restrict__ Bh, const u16* __restrict__ Bl,
    void* __restrict__ C0, void* __restrict__ C1,
    int M, int N, int K, int kbeg, int kend, float scale, u16* lds) {
    u16* Ash = lds;             // [128][32]
    u16* Bsh = lds + 4096;
    u16* Asl = lds + 8192;      // used only when SPLIT
    u16* Bsl = lds + 12288;

    const int tid  = threadIdx.x;
    const int wave = tid >> 6;
    const int lane = tid & 63;
    const int brow = blockIdx.x * 128;
    const int bcol = blockIdx.y * 128;
    const int wr = wave >> 1, wc = wave & 1;
    const int fr = lane & 15, fq = lane >> 4;

    f32x4 acc[4][4] = {};

    const int srow = wave * 32 + (lane >> 2);   // staging row in tile
    const int scol = (lane & 3) * 8;            // staging col (ushort)

    for (int k0 = kbeg; k0 < kend; k0 += 32) {
        const size_t aoff = (size_t)(brow + srow) * K + k0 + scol;
        const size_t boff = (size_t)(bcol + srow) * K + k0 + scol;
        u16* la = Ash + wave * 1024;            // wave-uniform LDS dest
        u16* lb = Bsh + wave * 1024;
        gload16(Ah + aoff, la);
        gload16(Ah + aoff + (size_t)16 * K, la + 512);
        gload16(Bh + boff, lb);
        gload16(Bh + boff + (size_t)16 * K, lb + 512);
        if (SPLIT) {
            u16* la2 = Asl + wave * 1024;
            u16* lb2 = Bsl + wave * 1024;
            gload16(Al + aoff, la2);
            gload16(Al + aoff + (size_t)16 * K, la2 + 512);
            gload16(Bl + boff, lb2);
            gload16(Bl + boff + (size_t)16 * K, lb2 + 512);
        }
        __syncthreads();

        bf16x8 af[4], bg[4], afl[4], bgl[4];
#pragma unroll
        for (int m = 0; m < 4; ++m)
            af[m] = *(const bf16x8*)&Ash[(wr * 64 + m * 16 + fr) * 32 + fq * 8];
#pragma unroll
        for (int n = 0; n < 4; ++n)
            bg[n] = *(const bf16x8*)&Bsh[(wc * 64 + n * 16 + fr) * 32 + fq * 8];
        if (SPLIT) {
#pragma unroll
            for (int m = 0; m < 4; ++m)
                afl[m] = *(const bf16x8*)&Asl[(wr * 64 + m * 16 + fr) * 32 + fq * 8];
#pragma unroll
            for (int n = 0; n < 4; ++n)
                bgl[n] = *(const bf16x8*)&Bsl[(wc * 64 + n * 16 + fr) * 32 + fq * 8];
        }
#pragma unroll
        for (int m = 0; m < 4; ++m)
#pragma unroll
            for (int n = 0; n < 4; ++n) {
                acc[m][n] = __builtin_amdgcn_mfma_f32_16x16x32_bf16(
                    af[m], bg[n], acc[m][n], 0, 0, 0);
                if (SPLIT) {
                    acc[m][n] = __builtin_amdgcn_mfma_f32_16x16x32_bf16(
                        af[m], bgl[n], acc[m][n], 0, 0, 0);
                    acc[m][n] = __builtin_amdgcn_mfma_f32_16x16x32_bf16(
                        afl[m], bg[n], acc[m][n], 0, 0, 0);
                }
            }
        __syncthreads();
    }

#pragma unroll
    for (int m = 0; m < 4; ++m)
#pragma unroll
        for (int n = 0; n < 4; ++n)
#pragma unroll
            for (int r = 0; r < 4; ++r) {
                int row = brow + wr * 64 + m * 16 + fq * 4 + r;
                int col = bcol + wc * 64 + n * 16 + fr;
                float v = acc[m][n][r] * scale;
                if (EPI == 0) {
                    ((float*)C0)[(size_t)row * N + col] = v;
                } else if (EPI == 1) {
                    u16 h = f2bf(v);
                    ((u16*)C0)[(size_t)row * N + col] = h;
                    ((u16*)C1)[(size_t)row * N + col] = f2bf(v - bf2f(h));
                } else {
                    ((u16*)C0)[(size_t)col * M + row] = f2bf(v);  // transposed
                }
            }
}

// fused Q/K/V projections in ONE dispatch: grid (32,8,3), z selects matrix.
// 768 blocks -> ~3 blocks/CU co-residency (vs 1/CU for separate launches).
__global__ __launch_bounds__(256) void proj_qkv(
    const u16* __restrict__ x1h, const u16* __restrict__ x1l,
    const u16* __restrict__ x2h, const u16* __restrict__ x2l,
    const u16* __restrict__ Wqh, const u16* __restrict__ Wql,
    const u16* __restrict__ Wkh, const u16* __restrict__ Wkl,
    const u16* __restrict__ Wvh,
    u16* __restrict__ Qh, u16* __restrict__ Ql,
    u16* __restrict__ Kh, u16* __restrict__ Kl, u16* __restrict__ Vt) {
    extern __shared__ u16 lds[];
    if (blockIdx.z == 0)
        gemm_bt_body<1, 1>(x1h, x1l, Wqh, Wql, Qh, Ql,
                           S1N, 1024, DIN, 0, DIN, 1.0f, lds);
    else if (blockIdx.z == 1)
        gemm_bt_body<1, 1>(x2h, x2l, Wkh, Wkl, Kh, Kl,
                           S2N, 1024, DIN, 0, DIN, 1.0f, lds);
    else
        gemm_bt_body<0, 2>(x2h, nullptr, Wvh, nullptr, Vt, nullptr,
                           S2N, 1024, DIN, 0, DIN, 1.0f, lds);
}

// PV with split-K4: grid (32,8,4), z owns K range [z*1024,(z+1)*1024) and
// partial buffer Oz. 1024 blocks -> 4/CU (the 873 TF occupancy regime).
__global__ __launch_bounds__(256) void pv_splitk(
    const u16* __restrict__ P, const u16* __restrict__ Vt,
    float* __restrict__ O0, float* __restrict__ O1,
    float* __restrict__ O2, float* __restrict__ O3) {
    extern __shared__ u16 lds[];
    float* O = blockIdx.z == 0 ? O0 : blockIdx.z == 1 ? O1
             : blockIdx.z == 2 ? O2 : O3;
    const int kbeg = blockIdx.z * 1024;
    gemm_bt_body<0, 0>(P, nullptr, Vt, nullptr, O, nullptr,
                       S1N, 1024, S2N, kbeg, kbeg + 1024, 1.0f, lds);
}

// final reduction of the 4 PV partials
__global__ __launch_bounds__(256) void add4(
    const float* __restrict__ a, const float* __restrict__ b,
    const float* __restrict__ c, const float* __restrict__ d,
    float* __restrict__ o) {
    size_t i = (size_t)(blockIdx.x * 256 + threadIdx.x) * 4;
    f32x4 va = *(const f32x4*)&a[i];
    f32x4 vb = *(const f32x4*)&b[i];
    f32x4 vc = *(const f32x4*)&c[i];
    f32x4 vd = *(const f32x4*)&d[i];
    *(f32x4*)&o[i] = (va + vb) + (vc + vd);
}

// ---------------------------------------------------------------------------
// Pipelined split S-GEMM: S[4096,4096] = Q K^T, hi/lo bf16 split, f32 out.
// BM=BN=256, BK=32, 512 threads (8 waves, 2x4), per-wave 128x64 out.
// LDS: 2 x 64KB buffers, each {Ah,Al,Bh,Bl} of 256x32 u16 (16KB each).
// Per K-tile 3 phases (one per split product); counted vmcnt(4)/(6)/(6)
// keeps 8 loads in flight across barriers. 16B-slot XOR swizzle
// (slot ^= (row>>1)&3) applied on pre-swizzled global source + ds_read.
__global__ __launch_bounds__(512, 2) void gemm_s_pipe(
    const u16* __restrict__ QH, const u16* __restrict__ QL,
    const u16* __restrict__ KH, const u16* __restrict__ KL,
    float* __restrict__ S) {
    extern __shared__ u16 lds[];
    // unit offsets within a 32768-u16 buffer:
    //   AH: 0   AL: 8192   BH: 16384   BL: 24576

    const int tid  = threadIdx.x;
    const int wave = tid >> 6;
    const int lane = tid & 63;
    const int brow = blockIdx.x * 256;
    const int bcol = blockIdx.y * 256;
    const int wr = wave >> 2;          // 0..1 -> rows wr*128
    const int wc = wave & 3;           // 0..3 -> cols wc*64
    const int fr = lane & 15, fq = lane >> 4;
    const int sl = fq ^ ((fr >> 1) & 3);              // swizzled 16B slot
    const int aoff = (wr * 128 + fr) * 32 + sl * 8;   // u16 offset, frag m adds m*512
    const int boff = (wc * 64 + fr) * 32 + sl * 8;    // frag n adds n*512
    const int wb = wave * 512;                        // wave-uniform stage base (u16)

    f32x4 acc[8][4] = {};

    // stage one 256x32 unit of matrix g (row-major, ld=1024) for k-tile at k0
    // into LDS unit lu. Source slot pre-swizzled so linear LDS dest ends up
    // swizzled: LDS[row][s'] = G[row][s' ^ ((row>>1)&3)].
    auto stage256 = [&](const u16* __restrict__ g, int grow0, int k0, u16* lu) {
#pragma unroll
        for (int j = 0; j < 2; ++j) {
            const int idx = j * 512 + tid;
            const int row = idx >> 2;
            const int gs  = (idx & 3) ^ ((row >> 1) & 3);
            gload16(g + (size_t)(grow0 + row) * 1024 + k0 + gs * 8,
                    lu + j * 4096 + wb);
        }
    };

    // prologue: tile 0 into buf0, in consumption order AH,BH,BL,AL (8 loads)
    stage256(QH, brow, 0, lds + 0);
    stage256(KH, bcol, 0, lds + 16384);
    stage256(KL, bcol, 0, lds + 24576);
    stage256(QL, brow, 0, lds + 8192);

    for (int t = 0; t < 32; ++t) {
        u16* cur = lds + (t & 1) * 32768;
        u16* nxt = lds + ((t + 1) & 1) * 32768;
        const int k1 = (t < 31 ? t + 1 : 31) * 32;   // clamp: last tile re-stages

        bf16x8 ah[8], al[8], bh[4], bl[4];

        // ---- phase 0: Ah x Bh  (needs AH[t], BH[t] = oldest 4 loads)
        WAIT_VM(4);
        __builtin_amdgcn_s_barrier();
        FENCE();
        stage256(QH, brow, k1, nxt + 0);
        stage256(KH, bcol, k1, nxt + 16384);
#pragma unroll
        for (int m = 0; m < 8; ++m)
            ah[m] = *(const bf16x8*)&cur[aoff + m * 512];
#pragma unroll
        for (int n = 0; n < 4; ++n)
            bh[n] = *(const bf16x8*)&cur[16384 + boff + n * 512];
        LGKM0();
        __builtin_amdgcn_sched_barrier(0);
        __builtin_amdgcn_s_setprio(1);
#pragma unroll
        for (int m = 0; m < 8; ++m)
#pragma unroll
            for (int n = 0; n < 4; ++n)
                acc[m][n] = __builtin_amdgcn_mfma_f32_16x16x32_bf16(
                    ah[m], bh[n], acc[m][n], 0, 0, 0);
        __builtin_amdgcn_s_setprio(0);

        // ---- phase 1: Ah x Bl  (needs BL[t] = oldest 2 of 8 outstanding)
        WAIT_VM(6);
        __builtin_amdgcn_s_barrier();
        FENCE();
        stage256(KL, bcol, k1, nxt + 24576);
#pragma unroll
        for (int n = 0; n < 4; ++n)
            bl[n] = *(const bf16x8*)&cur[24576 + boff + n * 512];
        LGKM0();
        __builtin_amdgcn_sched_barrier(0);
        __builtin_amdgcn_s_setprio(1);
#pragma unroll
        for (int m = 0; m < 8; ++m)
#pragma unroll
            for (int n = 0; n < 4; ++n)
                acc[m][n] = __builtin_amdgcn_mfma_f32_16x16x32_bf16(
                    ah[m], bl[n], acc[m][n], 0, 0, 0);
        __builtin_amdgcn_s_setprio(0);

        // ---- phase 2: Al x Bh  (needs AL[t] = oldest 2 of 8 outstanding)
        WAIT_VM(6);
        __builtin_amdgcn_s_barrier();
        FENCE();
        stage256(QL, brow, k1, nxt + 8192);
#pragma unroll
        for (int m = 0; m < 8; ++m)
            al[m] = *(const bf16x8*)&cur[8192 + aoff + m * 512];
        LGKM0();
        __builtin_amdgcn_sched_barrier(0);
        __builtin_amdgcn_s_setprio(1);
#pragma unroll
        for (int m = 0; m < 8; ++m)
#pragma unroll
            for (int n = 0; n < 4; ++n)
                acc[m][n] = __builtin_amdgcn_mfma_f32_16x16x32_bf16(
                    al[m], bh[n], acc[m][n], 0, 0, 0);
        __builtin_amdgcn_s_setprio(0);
    }
    asm volatile("s_waitcnt vmcnt(0)" ::: "memory");  // drain before endpgm

    // epilogue: C-layout row=(lane>>4)*4+reg, col=lane&15 per 16x16 frag
#pragma unroll
    for (int m = 0; m < 8; ++m)
#pragma unroll
        for (int n = 0; n < 4; ++n)
#pragma unroll
            for (int r = 0; r < 4; ++r) {
                int row = brow + wr * 128 + m * 16 + fq * 4 + r;
                int col = bcol + wc * 64 + n * 16 + fr;
                S[(size_t)row * S2N + col] = acc[m][n][r];
            }
}

// ---------------------------------------------------------------------------
// row softmax: P[row] = softmax(S[row] * scale), written as bf16.
// 16B-per-lane coalesced loads: thread t handles cols {(j*256+t)*4 .. +3}.
__global__ __launch_bounds__(256) void softmax_rows(const float* __restrict__ S,
                                                    u16* __restrict__ P, float c) {
    const int row = blockIdx.x;
    const float* s = S + (size_t)row * S2N;
    const int t = threadIdx.x;
    f32x4 v[4];
#pragma unroll
    for (int j = 0; j < 4; ++j) v[j] = *(const f32x4*)&s[(j * 256 + t) * 4];

    float mx = -3.4e38f;
#pragma unroll
    for (int j = 0; j < 4; ++j)
#pragma unroll
        for (int e = 0; e < 4; ++e) mx = fmaxf(mx, v[j][e]);
#pragma unroll
    for (int off = 32; off; off >>= 1) mx = fmaxf(mx, __shfl_xor(mx, off));
    __shared__ float redm[4], reds[4];
    if ((t & 63) == 0) redm[t >> 6] = mx;
    __syncthreads();
    mx = fmaxf(fmaxf(redm[0], redm[1]), fmaxf(redm[2], redm[3]));

    float sum = 0.f;
#pragma unroll
    for (int j = 0; j < 4; ++j)
#pragma unroll
        for (int e = 0; e < 4; ++e) {
            float ex = exp2f((v[j][e] - mx) * c);
            v[j][e] = ex;
            sum += ex;
        }
#pragma unroll
    for (int off = 32; off; off >>= 1) sum += __shfl_xor(sum, off);
    if ((t & 63) == 0) reds[t >> 6] = sum;
    __syncthreads();
    sum = (reds[0] + reds[1]) + (reds[2] + reds[3]);
    float rs = 1.0f / sum;

#pragma unroll
    for (int j = 0; j < 4; ++j) {
        u16x4 o;
#pragma unroll
        for (int e = 0; e < 4; ++e) o[e] = f2bf(v[j][e] * rs);
        *(u16x4*)&P[(size_t)row * S2N + (j * 256 + t) * 4] = o;
    }
}

// ---------------------------------------------------------------------------
extern "C" void kernel_launch(void* const* d_in, const int* in_sizes, int n_in,
                              void* d_out, int out_size, void* d_ws, size_t ws_size,
                              hipStream_t stream) {
    const float* x1 = (const float*)d_in[0];
    const float* x2 = (const float*)d_in[1];
    const float* Wq = (const float*)d_in[2];
    const float* Wk = (const float*)d_in[3];
    const float* Wv = (const float*)d_in[4];

    char* ws = (char*)d_ws;
    const size_t MB = 1024 * 1024;
    u16* Qh  = (u16*)(ws + 0 * MB);
    u16* Ql  = (u16*)(ws + 8 * MB);
    u16* Kh  = (u16*)(ws + 16 * MB);
    u16* Kl  = (u16*)(ws + 24 * MB);
    u16* Vt  = (u16*)(ws + 32 * MB);
    u16* x1h = (u16*)(ws + 40 * MB);
    u16* x1l = (u16*)(ws + 48 * MB);
    u16* x2h = (u16*)(ws + 56 * MB);
    u16* x2l = (u16*)(ws + 64 * MB);
    u16* Wqh = (u16*)(ws + 72 * MB);
    u16* Wql = (u16*)(ws + 74 * MB);
    u16* Wkh = (u16*)(ws + 76 * MB);
    u16* Wkl = (u16*)(ws + 78 * MB);
    u16* Wvh = (u16*)(ws + 80 * MB);
    u16* Wvl = (u16*)(ws + 82 * MB);
    float* Smat = (float*)(ws + 40 * MB);   // 64 MB, reuses cvt region
    u16* P   = (u16*)(ws + 0 * MB);         // 32 MB, reuses Q/K region
    float* O0 = (float*)(ws + 40 * MB);     // PV partials reuse dead Smat
    float* O1 = (float*)(ws + 56 * MB);
    float* O2 = (float*)(ws + 72 * MB);
    float* O3 = (float*)(ws + 88 * MB);

    // conversions (fused dispatches)
    split_cvt2<<<8192, 256, 0, stream>>>(x1, x1h, x1l, x2, x2h, x2l);
    wsplitT3<<<dim3(16, 16, 3), 256, 0, stream>>>(Wq, Wqh, Wql, Wk, Wkh, Wkl,
                                                  Wv, Wvh, Wvl);

    // Q,K,V projections in one dispatch (768 blocks)
    proj_qkv<<<dim3(32, 8, 3), 256, 32768, stream>>>(
        x1h, x1l, x2h, x2l, Wqh, Wql, Wkh, Wkl, Wvh, Qh, Ql, Kh, Kl, Vt);

    // scores S = Q K^T (split precision, f32 out) — pipelined 256x256 kernel
    gemm_s_pipe<<<dim3(16, 16), 512, 131072, stream>>>(Qh, Ql, Kh, Kl, Smat);

    // softmax(S/32) -> P (bf16);  c = (1/32) * log2(e)
    softmax_rows<<<4096, 256, 0, stream>>>(Smat, P, 0.04508422002778011f);

    // O = P V  (split-K4, 1024 blocks) + reduction
    pv_splitk<<<dim3(32, 8, 4), 256, 16384, stream>>>(P, Vt, O0, O1, O2, O3);
    add4<<<4096, 256, 0, stream>>>(O0, O1, O2, O3, (float*)d_out);
}